// Round 4
// baseline (704.129 us; speedup 1.0000x reference)
//
#include <hip/hip_runtime.h>
#include <hip/hip_bf16.h>
#include <cstdint>
#include <cmath>

#define AS1 __attribute__((address_space(1)))
#define AS3 __attribute__((address_space(3)))

typedef unsigned short u16;
typedef uint32_t u32;
typedef __attribute__((ext_vector_type(8))) __bf16 bf16x8;
typedef __attribute__((ext_vector_type(8))) unsigned short u16x8;
typedef __attribute__((ext_vector_type(4))) float f32x4;

// fp32 -> bf16 round-to-nearest-even
__device__ __forceinline__ u16 f2bf(float f) {
    uint32_t u = __builtin_bit_cast(uint32_t, f);
    return (u16)((u + 0x7fffu + ((u >> 16) & 1u)) >> 16);
}

// order-preserving float -> u32 map (for integer atomicMax); 0 is below all reals
__device__ __forceinline__ u32 f2ord(float f) {
    u32 u = __builtin_bit_cast(u32, f);
    return u ^ (u32)(((int32_t)u >> 31) | 0x80000000);
}
__device__ __forceinline__ float ord2f(u32 v) {
    u32 u = (v & 0x80000000u) ? (v ^ 0x80000000u) : ~v;
    return __builtin_bit_cast(float, u);
}

// ---------------- conversion kernels ----------------

// x [32768,128] fp32 -> bf16, 8 elems/thread
__global__ void cvt_x(const float* __restrict__ x, u16* __restrict__ xb) {
    long idx = (long)(blockIdx.x * 256 + threadIdx.x) * 8;
    float4 a = *(const float4*)(x + idx);
    float4 b = *(const float4*)(x + idx + 4);
    u16x8 o;
    o[0]=f2bf(a.x); o[1]=f2bf(a.y); o[2]=f2bf(a.z); o[3]=f2bf(a.w);
    o[4]=f2bf(b.x); o[5]=f2bf(b.y); o[6]=f2bf(b.z); o[7]=f2bf(b.w);
    *(u16x8*)(xb + idx) = o;
}

// W1 = [Wd(511); Wa(512); zeros(1)] -> bf16 [1024,128]; bias bb[1024]
__global__ void build_w1(const float* __restrict__ Wd, const float* __restrict__ bd,
                         const float* __restrict__ Wa, const float* __restrict__ ba,
                         u16* __restrict__ w1b, float* __restrict__ bb) {
    int t = blockIdx.x * 256 + threadIdx.x;   // 16384 threads
    int row = t >> 4, g = (t & 15) * 8;
    const float* src = nullptr;
    if (row < 511)       src = Wd + row * 128 + g;
    else if (row < 1023) src = Wa + (row - 511) * 128 + g;
    u16x8 o = 0;
    if (src) {
        #pragma unroll
        for (int j = 0; j < 8; ++j) o[j] = f2bf(src[j]);
    }
    *(u16x8*)(w1b + row * 128 + g) = o;
    if ((t & 15) == 0)
        bb[row] = row < 511 ? bd[row] : (row < 1023 ? ba[row - 511] : 0.f);
}

// Wl [1024,2046] fp32 -> bf16 [1024,2048], with the second half SHIFTED +1:
// out col c: c<1023 -> Wl[:,c]; c==1023 -> 0; 1024<=c<=2046 -> Wl[:,c-1]; c==2047 -> 0
// (matches hh layout: pos block at cols 0..1023, neg block at cols 1024..2047)
__global__ void build_wl(const float* __restrict__ Wl, u16* __restrict__ wlb) {
    int t = blockIdx.x * 256 + threadIdx.x;   // 262144 threads
    int row = t >> 8, g = (t & 255) * 8;
    const float* src = Wl + (long)row * 2046;
    u16x8 o;
    #pragma unroll
    for (int j = 0; j < 8; ++j) {
        int c = g + j;
        float v;
        if (c == 1023 || c == 2047) v = 0.f;
        else v = (c < 1023) ? src[c] : src[c - 1];
        o[j] = f2bf(v);
    }
    *(u16x8*)(wlb + (long)row * 2048 + g) = o;
}

// ---------------- MFMA GEMM: C = A(bf16,[M,K]) * B(bf16,[N,K])^T ----------------
// BM=BN=128, BK=32; block=256 threads (4 waves, 2x2), wave tile 64x64 (4x4 of 16x16x32)
// 1-D grid of 2048, XCD-aware swizzle: xcd=b&7 owns mTiles [xcd*32, xcd*32+32), so the
// 8 nTiles sharing an A-tile run on ONE XCD -> A fetched once per XCD L2.
// MODE 0: fused ragged-max epilogue -> pooledPart[nTile][row][16] as ordered u32
// MODE 1: hh epilogue, LDS-staged coalesced stores:
//         hh[row, blockN+c]      = relu(v+b)
//         hh[row, 1024+blockN+c] = relu(-(v+b))
template <int MODE>
__global__ __launch_bounds__(256) void gemm_mfma(
        const u16* __restrict__ A, const u16* __restrict__ B, int K,
        u16* __restrict__ outH, const float* __restrict__ bias,
        const int* __restrict__ seg, u32* __restrict__ pp) {
    __shared__ union SharedU {
        struct { u16 As[128 * 32]; u16 Bs[128 * 32]; } s;  // 16384 B (K-loop)
        u32 pmax[128 * 16];                                 //  8192 B (MODE 0 epilogue)
        u16 obuf[64 * 144];                                 // 18432 B (MODE 1 epilogue)
    } sh;
    const int tid  = threadIdx.x;
    const int lane = tid & 63, wave = tid >> 6;
    const int wy = wave >> 1, wx = wave & 1;
    const int i16 = lane & 15, q = lane >> 4;

    const int b = blockIdx.x;
    const int xcd = b & 7, i = b >> 3;
    const int nTile = i & 7;
    const long blockM = (long)(xcd * 32 + (i >> 3)) * 128;
    const int  blockN = nTile * 128;

    f32x4 acc[4][4];
    #pragma unroll
    for (int m = 0; m < 4; ++m)
        #pragma unroll
        for (int n = 0; n < 4; ++n)
            acc[m][n] = f32x4{0.f, 0.f, 0.f, 0.f};

    // staging: chunk c covers 16 rows x 32 cols; lane l -> row c*16 + l/4, col (l%4)*8
    const int cA   = wave * 2;
    const int srow = lane >> 2;
    const int scol = (lane & 3) * 8;
    const u16* a0 = A + (blockM + cA * 16 + srow) * (long)K + scol;
    const u16* a1 = A + (blockM + (cA + 1) * 16 + srow) * (long)K + scol;
    const u16* b0 = B + ((long)blockN + cA * 16 + srow) * K + scol;
    const u16* b1 = B + ((long)blockN + (cA + 1) * 16 + srow) * K + scol;

    for (int k0 = 0; k0 < K; k0 += 32) {
        __builtin_amdgcn_global_load_lds((const AS1 void*)(a0 + k0), (AS3 void*)&sh.s.As[cA * 512],       16, 0, 0);
        __builtin_amdgcn_global_load_lds((const AS1 void*)(a1 + k0), (AS3 void*)&sh.s.As[(cA + 1) * 512], 16, 0, 0);
        __builtin_amdgcn_global_load_lds((const AS1 void*)(b0 + k0), (AS3 void*)&sh.s.Bs[cA * 512],       16, 0, 0);
        __builtin_amdgcn_global_load_lds((const AS1 void*)(b1 + k0), (AS3 void*)&sh.s.Bs[(cA + 1) * 512], 16, 0, 0);
        __syncthreads();

        bf16x8 af[4], bfv[4];
        #pragma unroll
        for (int s = 0; s < 4; ++s) {
            af[s]  = *(const bf16x8*)&sh.s.As[(wy * 64 + s * 16 + i16) * 32 + q * 8];
            bfv[s] = *(const bf16x8*)&sh.s.Bs[(wx * 64 + s * 16 + i16) * 32 + q * 8];
        }
        #pragma unroll
        for (int sm = 0; sm < 4; ++sm)
            #pragma unroll
            for (int sn = 0; sn < 4; ++sn)
                acc[sm][sn] = __builtin_amdgcn_mfma_f32_16x16x32_bf16(af[sm], bfv[sn], acc[sm][sn], 0, 0, 0);
        __syncthreads();
    }

    // epilogue: D[row = 4q + r][col = i16] per 16x16 subtile (verified C/D layout)
    if (MODE == 0) {
        // zero the (overlaid) per-block pooled-max table, then LDS atomicMax
        #pragma unroll
        for (int j = 0; j < 8; ++j) sh.pmax[tid + j * 256] = 0u;   // 0 = below all reals
        __syncthreads();
        int segc[4];
        #pragma unroll
        for (int sn = 0; sn < 4; ++sn) segc[sn] = seg[blockN + wx * 64 + sn * 16 + i16];
        #pragma unroll
        for (int sm = 0; sm < 4; ++sm) {
            #pragma unroll
            for (int sn = 0; sn < 4; ++sn) {
                #pragma unroll
                for (int r = 0; r < 4; ++r) {
                    const int rl = wy * 64 + sm * 16 + 4 * q + r;
                    atomicMax(&sh.pmax[rl * 16 + segc[sn]], f2ord(acc[sm][sn][r]));
                }
            }
        }
        __syncthreads();
        // write partials: pp[nTile][blockM + rl][a]
        #pragma unroll
        for (int j = 0; j < 8; ++j) {
            int idx = tid + j * 256;                       // 0..2047
            pp[((long)nTile << 19) + ((blockM + (idx >> 4)) << 4) + (idx & 15)] = sh.pmax[idx];
        }
    } else {
        float bv[4];
        #pragma unroll
        for (int sn = 0; sn < 4; ++sn) bv[sn] = bias[blockN + wx * 64 + sn * 16 + i16];
        // 4 passes: sign (pos/neg) x rowHalf; stage 64x128 bf16 in LDS, store coalesced.
        // Store phase: 64 rows x 128 cols = 8192 u16; 256 thr x 8 u16 -> 4 row-groups.
        #pragma unroll
        for (int sg = 0; sg < 2; ++sg) {
            #pragma unroll
            for (int rh = 0; rh < 2; ++rh) {
                __syncthreads();
                if (wy == rh) {
                    #pragma unroll
                    for (int sm = 0; sm < 4; ++sm)
                        #pragma unroll
                        for (int sn = 0; sn < 4; ++sn)
                            #pragma unroll
                            for (int r = 0; r < 4; ++r) {
                                const float v = acc[sm][sn][r] + bv[sn];
                                const float pv = sg ? fmaxf(-v, 0.f) : fmaxf(v, 0.f);
                                sh.obuf[(sm * 16 + 4 * q + r) * 144 + wx * 64 + sn * 16 + i16] = f2bf(pv);
                            }
                }
                __syncthreads();
                const int gcol = (sg ? 1024 : 0) + blockN + (tid & 15) * 8;
                #pragma unroll
                for (int rr = 0; rr < 4; ++rr) {
                    const int row = rr * 16 + (tid >> 4);
                    const long grow = blockM + rh * 64 + row;
                    *(u16x8*)&outH[grow * 2048 + gcol] =
                        *(const u16x8*)&sh.obuf[row * 144 + (tid & 15) * 8];
                }
            }
        }
    }
}

// ---------------- finalize: max over 8 partials + softmax ----------------
// 256 threads = 16 rows x 16 actions per block; shuffle softmax over width 16
__global__ __launch_bounds__(256) void finalize(const u32* __restrict__ pp,
                                                float* __restrict__ out) {
    const int tid = threadIdx.x;
    const long row = (long)blockIdx.x * 16 + (tid >> 4);
    const int t = tid & 15;
    u32 m = 0;
    #pragma unroll
    for (int p = 0; p < 8; ++p)
        m = max(m, pp[((long)p << 19) + (row << 4) + t]);
    float logit = ord2f(m);
    float rm = logit;
    #pragma unroll
    for (int d = 8; d >= 1; d >>= 1) rm = fmaxf(rm, __shfl_xor(rm, d, 16));
    float e = __expf(logit - rm);
    float s = e;
    #pragma unroll
    for (int d = 8; d >= 1; d >>= 1) s += __shfl_xor(s, d, 16);
    out[(row << 4) + t] = e / s;
}

// ---------------- launch ----------------
extern "C" void kernel_launch(void* const* d_in, const int* in_sizes, int n_in,
                              void* d_out, int out_size, void* d_ws, size_t ws_size,
                              hipStream_t stream) {
    const float* x  = (const float*)d_in[0];
    const float* Wd = (const float*)d_in[1];
    const float* bd = (const float*)d_in[2];
    const float* Wa = (const float*)d_in[3];
    const float* ba = (const float*)d_in[4];
    const float* Wl = (const float*)d_in[5];
    const int*  seg = (const int*)d_in[6];
    float* out = (float*)d_out;

    char* ws = (char*)d_ws;
    u16*   xb  = (u16*)(ws);                       //   8,388,608 B  x bf16 [32768,128]
    u16*   w1b = (u16*)(ws + 8388608);             //     262,144 B  W1 bf16 [1024,128]
    float* bb  = (float*)(ws + 8650752);           //       4,096 B  bias [1024]
    u16*   wlb = (u16*)(ws + 8654848);             //   4,194,304 B  Wl bf16 [1024,2048] (cols permuted)
    u16*   hh  = (u16*)(ws + 12849152);            // 134,217,728 B  hh bf16 [32768,2048]
    u32*   pp  = (u32*)(ws + 147066880);           //  16,777,216 B  pooledPart u32 [8][32768][16]
    // total ws use: 163,844,096 B (~156 MiB)

    cvt_x   <<<2048, 256, 0, stream>>>(x, xb);
    build_w1<<<64,   256, 0, stream>>>(Wd, bd, Wa, ba, w1b, bb);
    build_wl<<<1024, 256, 0, stream>>>(Wl, wlb);
    gemm_mfma<1><<<2048, 256, 0, stream>>>(xb, w1b, 128, hh, bb, nullptr, nullptr);
    gemm_mfma<0><<<2048, 256, 0, stream>>>(hh, wlb, 2048, nullptr, nullptr, seg, pp);
    finalize<<<2048, 256, 0, stream>>>(pp, out);
}

// Round 5
// 328.447 us; speedup vs baseline: 2.1438x; 2.1438x over previous
//
#include <hip/hip_runtime.h>
#include <hip/hip_bf16.h>
#include <cstdint>
#include <cmath>

#define AS1 __attribute__((address_space(1)))
#define AS3 __attribute__((address_space(3)))

typedef unsigned short u16;
typedef uint32_t u32;
typedef __attribute__((ext_vector_type(8))) __bf16 bf16x8;
typedef __attribute__((ext_vector_type(8))) unsigned short u16x8;
typedef __attribute__((ext_vector_type(4))) float f32x4;

// fp32 -> bf16 round-to-nearest-even
__device__ __forceinline__ u16 f2bf(float f) {
    uint32_t u = __builtin_bit_cast(uint32_t, f);
    return (u16)((u + 0x7fffu + ((u >> 16) & 1u)) >> 16);
}

// order-preserving float -> u32 map (for integer atomicMax); 0 is below all reals
__device__ __forceinline__ u32 f2ord(float f) {
    u32 u = __builtin_bit_cast(u32, f);
    return u ^ (u32)(((int32_t)u >> 31) | 0x80000000);
}
__device__ __forceinline__ float ord2f(u32 v) {
    u32 u = (v & 0x80000000u) ? (v ^ 0x80000000u) : ~v;
    return __builtin_bit_cast(float, u);
}

// ---------------- conversion kernels ----------------

// x [32768,128] fp32 -> bf16, 8 elems/thread
__global__ void cvt_x(const float* __restrict__ x, u16* __restrict__ xb) {
    long idx = (long)(blockIdx.x * 256 + threadIdx.x) * 8;
    float4 a = *(const float4*)(x + idx);
    float4 b = *(const float4*)(x + idx + 4);
    u16x8 o;
    o[0]=f2bf(a.x); o[1]=f2bf(a.y); o[2]=f2bf(a.z); o[3]=f2bf(a.w);
    o[4]=f2bf(b.x); o[5]=f2bf(b.y); o[6]=f2bf(b.z); o[7]=f2bf(b.w);
    *(u16x8*)(xb + idx) = o;
}

// W1 = [Wd(511); Wa(512); zeros(1)] -> bf16 [1024,128]; bias bb[1024]
__global__ void build_w1(const float* __restrict__ Wd, const float* __restrict__ bd,
                         const float* __restrict__ Wa, const float* __restrict__ ba,
                         u16* __restrict__ w1b, float* __restrict__ bb) {
    int t = blockIdx.x * 256 + threadIdx.x;   // 16384 threads
    int row = t >> 4, g = (t & 15) * 8;
    const float* src = nullptr;
    if (row < 511)       src = Wd + row * 128 + g;
    else if (row < 1023) src = Wa + (row - 511) * 128 + g;
    u16x8 o = 0;
    if (src) {
        #pragma unroll
        for (int j = 0; j < 8; ++j) o[j] = f2bf(src[j]);
    }
    *(u16x8*)(w1b + row * 128 + g) = o;
    if ((t & 15) == 0)
        bb[row] = row < 511 ? bd[row] : (row < 1023 ? ba[row - 511] : 0.f);
}

// Wl [1024,2046] fp32 -> bf16 [1024,2048], second half SHIFTED +1:
// out col c: c<1023 -> Wl[:,c]; c==1023 -> 0; 1024<=c<=2046 -> Wl[:,c-1]; c==2047 -> 0
// (matches hh layout: pos block at cols 0..1023, neg block at cols 1024..2047)
__global__ void build_wl(const float* __restrict__ Wl, u16* __restrict__ wlb) {
    int t = blockIdx.x * 256 + threadIdx.x;   // 262144 threads
    int row = t >> 8, g = (t & 255) * 8;
    const float* src = Wl + (long)row * 2046;
    u16x8 o;
    #pragma unroll
    for (int j = 0; j < 8; ++j) {
        int c = g + j;
        float v;
        if (c == 1023 || c == 2047) v = 0.f;
        else v = (c < 1023) ? src[c] : src[c - 1];
        o[j] = f2bf(v);
    }
    *(u16x8*)(wlb + (long)row * 2048 + g) = o;
}

// ---------------- MFMA GEMM: C = A(bf16,[M,K]) * B(bf16,[N,K])^T ----------------
// BM=BN=128, BK=32; block=256 threads (4 waves, 2x2), wave tile 64x64 (4x4 of 16x16x32).
// Grid dim3(8,256): linear ID = x + 8y -> XCD = x (round-robin). mTile = x*32 + (y>>3),
// nTile = y&7: the 8 blocks sharing an A-tile all land on XCD x -> A fetched once/XCD L2.
// K-loop start offset koff depends on (y>>3): same-A blocks stay K-phase-aligned (L2
// temporal reuse), different tile-groups co-resident on a CU are de-synchronized
// (anti LDS-crossbar-burst; round-4 regression showed 2.4e8 conflict cycles).
// MODE 0: fused ragged-max epilogue -> pooledPart[nTile][row][16] as ordered u32
// MODE 1: hh epilogue (scattered stores, L2 absorbs):
//         hh[row, col] = relu(v+b), hh[row, 1024+col] = relu(-(v+b)), col in 0..1023
template <int MODE>
__global__ __launch_bounds__(256) void gemm_mfma(
        const u16* __restrict__ A, const u16* __restrict__ B, int K,
        u16* __restrict__ outH, const float* __restrict__ bias,
        const int* __restrict__ seg, u32* __restrict__ pp) {
    __shared__ u16 As[128 * 32];
    __shared__ u16 Bs[128 * 32];
    __shared__ u32 pmax[128 * 16];
    const int tid  = threadIdx.x;
    const int lane = tid & 63, wave = tid >> 6;
    const int wy = wave >> 1, wx = wave & 1;
    const int i16 = lane & 15, q = lane >> 4;

    const int xcd = blockIdx.x;                 // 0..7
    const int y   = blockIdx.y;                 // 0..255
    const int nTile = y & 7;
    const long blockM = (long)(xcd * 32 + (y >> 3)) * 128;
    const int  blockN = nTile * 128;
    const int nch  = K >> 5;                    // K chunks of 32
    const int koff = ((y >> 3) * 2) & (nch - 1);

    if (MODE == 0) {
        #pragma unroll
        for (int j = 0; j < 8; ++j) pmax[tid + j * 256] = 0u;   // 0 = below all reals
        // first __syncthreads in the K-loop orders this before any epilogue atomics
    }

    f32x4 acc[4][4];
    #pragma unroll
    for (int m = 0; m < 4; ++m)
        #pragma unroll
        for (int n = 0; n < 4; ++n)
            acc[m][n] = f32x4{0.f, 0.f, 0.f, 0.f};

    // staging: chunk c covers 16 rows x 32 cols; lane l -> row c*16 + l/4, col (l%4)*8
    const int cA   = wave * 2;
    const int srow = lane >> 2;
    const int scol = (lane & 3) * 8;
    const u16* a0 = A + (blockM + cA * 16 + srow) * (long)K + scol;
    const u16* a1 = A + (blockM + (cA + 1) * 16 + srow) * (long)K + scol;
    const u16* b0 = B + ((long)blockN + cA * 16 + srow) * K + scol;
    const u16* b1 = B + ((long)blockN + (cA + 1) * 16 + srow) * K + scol;

    for (int it = 0; it < nch; ++it) {
        const int k0 = ((it + koff) & (nch - 1)) << 5;
        __builtin_amdgcn_global_load_lds((const AS1 void*)(a0 + k0), (AS3 void*)&As[cA * 512],       16, 0, 0);
        __builtin_amdgcn_global_load_lds((const AS1 void*)(a1 + k0), (AS3 void*)&As[(cA + 1) * 512], 16, 0, 0);
        __builtin_amdgcn_global_load_lds((const AS1 void*)(b0 + k0), (AS3 void*)&Bs[cA * 512],       16, 0, 0);
        __builtin_amdgcn_global_load_lds((const AS1 void*)(b1 + k0), (AS3 void*)&Bs[(cA + 1) * 512], 16, 0, 0);
        __syncthreads();

        bf16x8 af[4], bfv[4];
        #pragma unroll
        for (int s = 0; s < 4; ++s) {
            af[s]  = *(const bf16x8*)&As[(wy * 64 + s * 16 + i16) * 32 + q * 8];
            bfv[s] = *(const bf16x8*)&Bs[(wx * 64 + s * 16 + i16) * 32 + q * 8];
        }
        #pragma unroll
        for (int sm = 0; sm < 4; ++sm)
            #pragma unroll
            for (int sn = 0; sn < 4; ++sn)
                acc[sm][sn] = __builtin_amdgcn_mfma_f32_16x16x32_bf16(af[sm], bfv[sn], acc[sm][sn], 0, 0, 0);
        __syncthreads();
    }

    // epilogue: D[row = 4q + r][col = i16] per 16x16 subtile (verified C/D layout)
    if (MODE == 0) {
        int segc[4];
        #pragma unroll
        for (int sn = 0; sn < 4; ++sn) segc[sn] = seg[blockN + wx * 64 + sn * 16 + i16];
        #pragma unroll
        for (int sm = 0; sm < 4; ++sm) {
            #pragma unroll
            for (int sn = 0; sn < 4; ++sn) {
                #pragma unroll
                for (int r = 0; r < 4; ++r) {
                    const int rl = wy * 64 + sm * 16 + 4 * q + r;
                    atomicMax(&pmax[rl * 16 + segc[sn]], f2ord(acc[sm][sn][r]));
                }
            }
        }
        __syncthreads();
        // write partials: pp[nTile][blockM + rl][a]
        #pragma unroll
        for (int j = 0; j < 8; ++j) {
            int idx = tid + j * 256;                       // 0..2047
            pp[((long)nTile << 19) + ((blockM + (idx >> 4)) << 4) + (idx & 15)] = pmax[idx];
        }
    } else {
        float bv[4];
        #pragma unroll
        for (int sn = 0; sn < 4; ++sn) bv[sn] = bias[blockN + wx * 64 + sn * 16 + i16];
        #pragma unroll
        for (int sm = 0; sm < 4; ++sm)
            #pragma unroll
            for (int sn = 0; sn < 4; ++sn) {
                const int col = blockN + wx * 64 + sn * 16 + i16;   // 0..1023
                #pragma unroll
                for (int r = 0; r < 4; ++r) {
                    const long row = blockM + wy * 64 + sm * 16 + 4 * q + r;
                    const float v = acc[sm][sn][r] + bv[sn];
                    u16* hrow = outH + row * 2048;
                    hrow[col]        = f2bf(fmaxf(v, 0.f));
                    hrow[1024 + col] = f2bf(fmaxf(-v, 0.f));
                    // col==1023: W1 row 1023 == 0 & bias 0 -> writes exact 0s (K-pad)
                }
            }
    }
}

// ---------------- finalize: max over 8 partials + softmax ----------------
// 256 threads = 16 rows x 16 actions per block; shuffle softmax over width 16
__global__ __launch_bounds__(256) void finalize(const u32* __restrict__ pp,
                                                float* __restrict__ out) {
    const int tid = threadIdx.x;
    const long row = (long)blockIdx.x * 16 + (tid >> 4);
    const int t = tid & 15;
    u32 m = 0;
    #pragma unroll
    for (int p = 0; p < 8; ++p)
        m = max(m, pp[((long)p << 19) + (row << 4) + t]);
    float logit = ord2f(m);
    float rm = logit;
    #pragma unroll
    for (int d = 8; d >= 1; d >>= 1) rm = fmaxf(rm, __shfl_xor(rm, d, 16));
    float e = __expf(logit - rm);
    float s = e;
    #pragma unroll
    for (int d = 8; d >= 1; d >>= 1) s += __shfl_xor(s, d, 16);
    out[(row << 4) + t] = e / s;
}

// ---------------- launch ----------------
extern "C" void kernel_launch(void* const* d_in, const int* in_sizes, int n_in,
                              void* d_out, int out_size, void* d_ws, size_t ws_size,
                              hipStream_t stream) {
    const float* x  = (const float*)d_in[0];
    const float* Wd = (const float*)d_in[1];
    const float* bd = (const float*)d_in[2];
    const float* Wa = (const float*)d_in[3];
    const float* ba = (const float*)d_in[4];
    const float* Wl = (const float*)d_in[5];
    const int*  seg = (const int*)d_in[6];
    float* out = (float*)d_out;

    char* ws = (char*)d_ws;
    u16*   xb  = (u16*)(ws);                       //   8,388,608 B  x bf16 [32768,128]
    u16*   w1b = (u16*)(ws + 8388608);             //     262,144 B  W1 bf16 [1024,128]
    float* bb  = (float*)(ws + 8650752);           //       4,096 B  bias [1024]
    u16*   wlb = (u16*)(ws + 8654848);             //   4,194,304 B  Wl bf16 [1024,2048] (cols shifted)
    u16*   hh  = (u16*)(ws + 12849152);            // 134,217,728 B  hh bf16 [32768,2048]
    u32*   pp  = (u32*)(ws + 147066880);           //  16,777,216 B  pooledPart u32 [8][32768][16]
    // total ws use: 163,844,096 B (~156 MiB)

    cvt_x   <<<2048, 256, 0, stream>>>(x, xb);
    build_w1<<<64,   256, 0, stream>>>(Wd, bd, Wa, ba, w1b, bb);
    build_wl<<<1024, 256, 0, stream>>>(Wl, wlb);
    gemm_mfma<1><<<dim3(8, 256), 256, 0, stream>>>(xb, w1b, 128, hh, bb, nullptr, nullptr);
    gemm_mfma<0><<<dim3(8, 256), 256, 0, stream>>>(hh, wlb, 2048, nullptr, nullptr, seg, pp);
    finalize<<<2048, 256, 0, stream>>>(pp, out);
}